// Round 7
// baseline (544.552 us; speedup 1.0000x reference)
//
#include <hip/hip_runtime.h>
#include <cstdint>
#include <cstddef>

// C[4096,4096] = sum_r input[r] @ weight[r]^T  == GEMM M=N=4096, K=8192, fp32 out.
// R11: FUSED cast+GEMM. The standalone fp32->bf16 cast was ~245us at 1.5 TB/s
// (pattern-insensitive: R0 nt-strided == R1 contiguous-cached) — eliminated.
// The 8-phase deep-prefetch GEMM (R6: 224us, MfmaUtil 55%) now reg-stages:
// per phase, ISSUE 4x global_load_dwordx4 fp32 (pre-swizzled addrs) into a
// parity payload set (pE/pO), and convert+ds_write the set issued 2 phases
// earlier (~1400cyc lead > HBM latency). Same RNE f2bf -> bit-identical.
// Slot schedule (write = issue+2), region lifetimes re-verified:
//   P0 w:A0(t1) i:A1(t1) | P1 w:B1(t1) i:B0(t2) | P2 w:A1(t1) i:A0(t2)
//   P3 w:B0(t2) i:B1(t2) | P4 w:A0(t2) i:A1(t2) | P5 w:B1(t2) i:B0(t3)
//   P6 w:A1(t2) i:A0(t3) | P7 w:B0(t3) i:B1(t3)
// Prologue: direct-stage t0 x4 + B0(t1); preload pE=A0(t1), pO=B1(t1).

#define M_DIM 4096
#define N_DIM 4096
#define K_DIM 8192
#define K_LOCAL 1024
#define RANKS 8
#define NT 128  // K-tiles: RANKS * (K_LOCAL/64)

typedef __bf16 bf16x8 __attribute__((ext_vector_type(8)));
typedef unsigned short ushort8 __attribute__((ext_vector_type(8)));
typedef float f32x4 __attribute__((ext_vector_type(4)));

__device__ __forceinline__ unsigned short f2bf(float f) {
    unsigned int u = __float_as_uint(f);
    unsigned int r = (u + 0x7fffu + ((u >> 16) & 1u)) >> 16;
    return (unsigned short)r;
}

__device__ __forceinline__ bf16x8 pack8(f32x4 a, f32x4 b) {
    ushort8 o;
    o[0] = f2bf(a.x); o[1] = f2bf(a.y); o[2] = f2bf(a.z); o[3] = f2bf(a.w);
    o[4] = f2bf(b.x); o[5] = f2bf(b.y); o[6] = f2bf(b.z); o[7] = f2bf(b.w);
    return __builtin_bit_cast(bf16x8, o);
}

#define LGKM0() asm volatile("s_waitcnt lgkmcnt(0)" ::: "memory")
#define BAR()   __builtin_amdgcn_s_barrier()

__global__ __launch_bounds__(512, 2) void gemm_fused(
    const float* __restrict__ A,  // [R, M, K_LOCAL] fp32
    const float* __restrict__ B,  // [R, N, K_LOCAL] fp32
    float* __restrict__ C) {      // [M, N] fp32
    // Per-tensor-half regions: [buf][rowhalf][128 rows][64 k] bf16 (128B rows).
    // 16B chunk c of row r stored at chunk c ^ (r & 7) (0 conflicts, R3-R6).
    __shared__ __align__(16) unsigned short As[2][2][128][64];
    __shared__ __align__(16) unsigned short Bs[2][2][128][64];

    const int tid = threadIdx.x;   // 0..511
    const int lane = tid & 63;
    const int wave = tid >> 6;     // 0..7
    const int l15 = lane & 15;
    const int l4 = lane >> 4;      // 0..3
    const int wm2 = wave >> 2;     // 0..1 -> row block *128 (= A half read)
    const int wn4 = wave & 3;      // 0..3 -> col block *64

    // Bijective XCD swizzle: 256 blocks, each XCD owns a 4x8 tile sub-grid.
    const int bid = blockIdx.x;
    const int xcd = bid & 7;
    const int idx = bid >> 3;                       // 0..31
    const int trow = (xcd >> 1) * 4 + (idx >> 3);   // 0..15
    const int tcol = (xcd & 1) * 8 + (idx & 7);     // 0..15
    const int bm0 = trow * 256;
    const int bn0 = tcol * 256;

    // Stage unit = one tensor-half: 128 rows x 64 k = 1024 x 16B bf16 chunks;
    // li = i*512 + tid: row = li>>3, cpos = li&7, global chunk g = cpos^(row&7).
    // fp32 source: chunk = 8 floats at col g*8 (2x f32x4). LDS dst linear.
    const float* gAf[2];
    const float* gBf[2];
    int lo[2];
#pragma unroll
    for (int i = 0; i < 2; ++i) {
        int li = i * 512 + tid;
        int row = li >> 3;
        int g = (li & 7) ^ (row & 7);
        gAf[i] = A + (size_t)(bm0 + row) * K_LOCAL + g * 8;
        gBf[i] = B + (size_t)(bn0 + row) * K_LOCAL + g * 8;
        lo[i] = li * 8;  // ushort units = li*16 bytes
    }

    f32x4 pE[4], pO[4];  // payload sets (constant-indexed only)

    auto ISSUE = [&](f32x4* p, const float* const* gp, int t, int h) {
        const size_t off = (size_t)(t >> 4) * ((size_t)M_DIM * K_LOCAL)
                         + (size_t)((t & 15) << 6) + (size_t)h * (128 * K_LOCAL);
        p[0] = *(const f32x4*)(gp[0] + off);
        p[1] = *(const f32x4*)(gp[0] + off + 4);
        p[2] = *(const f32x4*)(gp[1] + off);
        p[3] = *(const f32x4*)(gp[1] + off + 4);
    };
    auto WRITE = [&](const f32x4* p, unsigned short* base) {
        *(bf16x8*)(base + lo[0]) = pack8(p[0], p[1]);
        *(bf16x8*)(base + lo[1]) = pack8(p[2], p[3]);
    };

    // Fragment reads: k-chunk c = ks*4 + l4 stored at c ^ (row&7); frag rows
    // are <mult of 16> + l15, so row&7 == l15&7.
    const int swzk0 = ((l4 + 0) ^ (l15 & 7)) * 8;  // ks = 0
    const int swzk1 = ((l4 + 4) ^ (l15 & 7)) * 8;  // ks = 1
    const int hb = wn4 >> 1;                        // B half for this wave
    const int brow_base = (wn4 & 1) * 64 + l15;     // B row within half

    f32x4 acc[8][4] = {};
    bf16x8 aR[8], a1R[8], b0R[4], b1R[4];

    auto LDA = [&](bf16x8* dst, int buf, int mh) {
#pragma unroll
        for (int m = 0; m < 4; ++m) {
            const unsigned short* rp = &As[buf][wm2][mh * 64 + m * 16 + l15][0];
            dst[m * 2 + 0] = *(const bf16x8*)(rp + swzk0);
            dst[m * 2 + 1] = *(const bf16x8*)(rp + swzk1);
        }
    };
    auto LDB = [&](bf16x8* dst, int buf, int nh) {
#pragma unroll
        for (int n = 0; n < 2; ++n) {
            const unsigned short* rp = &Bs[buf][hb][brow_base + nh * 32 + n * 16][0];
            dst[n * 2 + 0] = *(const bf16x8*)(rp + swzk0);
            dst[n * 2 + 1] = *(const bf16x8*)(rp + swzk1);
        }
    };
    auto MFMA16 = [&](const bf16x8* a, const bf16x8* b, int mh, int nh) {
        __builtin_amdgcn_s_setprio(1);
#pragma unroll
        for (int m = 0; m < 4; ++m)
#pragma unroll
            for (int n = 0; n < 2; ++n)
#pragma unroll
                for (int ks = 0; ks < 2; ++ks)
                    acc[mh * 4 + m][nh * 2 + n] = __builtin_amdgcn_mfma_f32_16x16x32_bf16(
                        a[m * 2 + ks], b[n * 2 + ks], acc[mh * 4 + m][nh * 2 + n], 0, 0, 0);
        __builtin_amdgcn_s_setprio(0);
    };

    // Prologue: direct-stage t0's 4 units + B0(t1) (sequential, once).
    ISSUE(pE, gAf, 0, 0); WRITE(pE, &As[0][0][0][0]);
    ISSUE(pE, gAf, 0, 1); WRITE(pE, &As[0][1][0][0]);
    ISSUE(pE, gBf, 0, 0); WRITE(pE, &Bs[0][0][0][0]);
    ISSUE(pE, gBf, 0, 1); WRITE(pE, &Bs[0][1][0][0]);
    ISSUE(pE, gBf, 1, 0); WRITE(pE, &Bs[1][0][0][0]);   // B0(t1)
    ISSUE(pE, gAf, 1, 0);   // pE = A0(t1), written at P0
    ISSUE(pO, gBf, 1, 1);   // pO = B1(t1), written at P1
    LGKM0(); BAR();

    for (int i = 0; i < NT / 2; ++i) {
        const int t1 = 2 * i + 1;
        const int t2 = (2 * i + 2) & (NT - 1);
        const int t3 = (2 * i + 3) & (NT - 1);
        // P0: w E=A0(t1)->buf1.A0 [free prev-P6] | i A1(t1)
        WRITE(pE, &As[1][0][0][0]); ISSUE(pE, gAf, t1, 1);
        LDA(aR, 0, 0); LDB(b0R, 0, 0);
        BAR(); LGKM0(); MFMA16(aR, b0R, 0, 0); BAR();
        // P1: w O=B1(t1)->buf1.B1 [free prev-P5] | i B0(t2)
        WRITE(pO, &Bs[1][1][0][0]); ISSUE(pO, gBf, t2, 0);
        LDB(b1R, 0, 1);
        BAR(); LGKM0(); MFMA16(aR, b1R, 0, 1); BAR();
        // P2: w E=A1(t1)->buf1.A1 [free prev-P6] | i A0(t2)
        WRITE(pE, &As[1][1][0][0]); ISSUE(pE, gAf, t2, 0);
        LDA(a1R, 0, 1);
        BAR(); LGKM0(); MFMA16(a1R, b0R, 1, 0); BAR();
        // P3: w O=B0(t2)->buf0.B0 [free P1] | i B1(t2)
        WRITE(pO, &Bs[0][0][0][0]); ISSUE(pO, gBf, t2, 1);
        BAR(); LGKM0(); MFMA16(a1R, b1R, 1, 1); BAR();
        // P4: w E=A0(t2)->buf0.A0 [free P2] | i A1(t2)
        WRITE(pE, &As[0][0][0][0]); ISSUE(pE, gAf, t2, 1);
        LDA(aR, 1, 0); LDB(b0R, 1, 0);
        BAR(); LGKM0(); MFMA16(aR, b0R, 0, 0); BAR();
        // P5: w O=B1(t2)->buf0.B1 [free P1] | i B0(t3)
        WRITE(pO, &Bs[0][1][0][0]); ISSUE(pO, gBf, t3, 0);
        LDB(b1R, 1, 1);
        BAR(); LGKM0(); MFMA16(aR, b1R, 0, 1); BAR();
        // P6: w E=A1(t2)->buf0.A1 [free P2] | i A0(t3)
        WRITE(pE, &As[0][1][0][0]); ISSUE(pE, gAf, t3, 0);
        LDA(a1R, 1, 1);
        BAR(); LGKM0(); MFMA16(a1R, b0R, 1, 0); BAR();
        // P7: w O=B0(t3)->buf1.B0 [free P5] | i B1(t3)
        WRITE(pO, &Bs[1][0][0][0]); ISSUE(pO, gBf, t3, 1);
        BAR(); LGKM0(); MFMA16(a1R, b1R, 1, 1); BAR();
    }

    // Epilogue: C/D layout col = lane&15, row = (lane>>4)*4 + reg.
#pragma unroll
    for (int m = 0; m < 8; ++m) {
        int row0 = bm0 + wm2 * 128 + m * 16 + l4 * 4;
#pragma unroll
        for (int n = 0; n < 4; ++n) {
            int col = bn0 + wn4 * 64 + n * 16 + l15;
#pragma unroll
            for (int rr = 0; rr < 4; ++rr)
                C[(size_t)(row0 + rr) * N_DIM + col] = acc[m][n][rr];
        }
    }
}

extern "C" void kernel_launch(void* const* d_in, const int* in_sizes, int n_in,
                              void* d_out, int out_size, void* d_ws, size_t ws_size,
                              hipStream_t stream) {
    const float* inp = (const float*)d_in[0];
    const float* wgt = (const float*)d_in[1];
    float* out = (float*)d_out;
    (void)d_ws; (void)ws_size;  // fused kernel needs no workspace
    gemm_fused<<<256, 512, 0, stream>>>(inp, wgt, out);
}

// Round 8
// 510.162 us; speedup vs baseline: 1.0674x; 1.0674x over previous
//
#include <hip/hip_runtime.h>
#include <cstdint>
#include <cstddef>

// C[4096,4096] = sum_r input[r] @ weight[r]^T  == GEMM M=N=4096, K=8192, fp32 out.
// Phase 1: fp32 -> bf16 cast, R0 version (~80us real; dur_us carries ~170us of
//          fixed non-kernel overhead discovered in R7 — cast is near roofline).
// Phase 2: R12: single-barrier 8-phase GEMM. R6's 2 BAR/phase cost ~200cyc
//          each (16/2-tiles ~= the whole 1700cyc/tile non-MFMA gap). Deep
//          5-7 phase stage->consume leads make 1 BAR/phase safe IF stage is
//          issued AFTER the MFMA: then every WAR pair (restage vs last
//          reader) is ordered by reader's LGKM0(q) < BAR(q+1) <= BAR(p) <
//          stage(p). vmcnt ledger re-closed: VM6 after P3/P7 stage retires
//          exactly the next tile's 8 loads (14->6 outstanding).
//          (R7 fusion rejected: 376us, VALU+ds_write serialized on the
//          barrier path. R5 read-ahead rejected: spills.)

#define M_DIM 4096
#define N_DIM 4096
#define K_DIM 8192
#define K_LOCAL 1024
#define RANKS 8
#define NT 128  // K-tiles: RANKS * (K_LOCAL/64)

typedef __bf16 bf16x8 __attribute__((ext_vector_type(8)));
typedef float f32x4 __attribute__((ext_vector_type(4)));

__device__ __forceinline__ unsigned short f2bf(float f) {
    unsigned int u = __float_as_uint(f);
    unsigned int r = (u + 0x7fffu + ((u >> 16) & 1u)) >> 16;
    return (unsigned short)r;
}

// ---------- Phase 1: linear fp32 -> bf16 cast (R0 version) ----------
__global__ __launch_bounds__(256) void convert_cast(
    const float* __restrict__ srcA, unsigned short* __restrict__ dstA,
    const float* __restrict__ srcB, unsigned short* __restrict__ dstB,
    int blocks_per_tensor) {
    const float* src = srcA;
    unsigned short* dst = dstA;
    int b = blockIdx.x;
    if (b >= blocks_per_tensor) { b -= blocks_per_tensor; src = srcB; dst = dstB; }
    size_t base = (size_t)b * 4096 + threadIdx.x * 4;
#pragma unroll
    for (int i = 0; i < 4; ++i) {
        size_t e = base + i * 1024;
        f32x4 v = __builtin_nontemporal_load((const f32x4*)(src + e));
        ushort4 o;
        o.x = f2bf(v.x); o.y = f2bf(v.y); o.z = f2bf(v.z); o.w = f2bf(v.w);
        *(ushort4*)(dst + e) = o;
    }
}

// ---------- Phase 2: 256^2 single-barrier 8-phase bf16 MFMA GEMM ----------
__device__ __forceinline__ void async_copy16(const unsigned short* g, unsigned short* l) {
    __builtin_amdgcn_global_load_lds(
        (const __attribute__((address_space(1))) void*)g,
        (__attribute__((address_space(3))) void*)l,
        16, 0, 0);
}

#define VM6()   asm volatile("s_waitcnt vmcnt(6)" ::: "memory")
#define VM0()   asm volatile("s_waitcnt vmcnt(0)" ::: "memory")
#define LGKM0() asm volatile("s_waitcnt lgkmcnt(0)" ::: "memory")
#define BAR()   __builtin_amdgcn_s_barrier()

__global__ __launch_bounds__(512, 2) void gemm_bf16(
    const unsigned short* __restrict__ A,  // [R, M, K_LOCAL] bf16
    const unsigned short* __restrict__ B,  // [R, N, K_LOCAL] bf16
    float* __restrict__ C) {               // [M, N] fp32
    // Per-tensor-half regions: [buf][rowhalf][128 rows][64 k] (128B rows).
    // 16B chunk c of row r stored at chunk c ^ (r & 7) (0 conflicts, R3-R6).
    __shared__ __align__(16) unsigned short As[2][2][128][64];
    __shared__ __align__(16) unsigned short Bs[2][2][128][64];

    const int tid = threadIdx.x;   // 0..511
    const int lane = tid & 63;
    const int wave = tid >> 6;     // 0..7
    const int l15 = lane & 15;
    const int l4 = lane >> 4;      // 0..3
    const int wm2 = wave >> 2;     // 0..1 -> row block *128 (= A half read)
    const int wn4 = wave & 3;      // 0..3 -> col block *64

    // Bijective XCD swizzle: 256 blocks, each XCD owns a 4x8 tile sub-grid.
    const int bid = blockIdx.x;
    const int xcd = bid & 7;
    const int idx = bid >> 3;                       // 0..31
    const int trow = (xcd >> 1) * 4 + (idx >> 3);   // 0..15
    const int tcol = (xcd & 1) * 8 + (idx & 7);     // 0..15
    const int bm0 = trow * 256;
    const int bn0 = tcol * 256;

    // Stage unit = one tensor-half: 128 rows x 64 k x 2B = 16KB = 1024 chunks;
    // li = i*512 + tid: row = li>>3, cpos = li&7, global chunk g = cpos^(row&7).
    const unsigned short* gA[2];
    const unsigned short* gB[2];
    int lo[2];
#pragma unroll
    for (int i = 0; i < 2; ++i) {
        int li = i * 512 + tid;
        int row = li >> 3;
        int g = (li & 7) ^ (row & 7);
        gA[i] = A + (size_t)(bm0 + row) * K_LOCAL + g * 8;
        gB[i] = B + (size_t)(bn0 + row) * K_LOCAL + g * 8;
        lo[i] = li * 8;  // ushort units
    }

    auto stageA = [&](int t, int buf, int h) {
        const size_t off = (size_t)(t >> 4) * ((size_t)M_DIM * K_LOCAL)
                         + (size_t)((t & 15) << 6) + (size_t)h * (128 * K_LOCAL);
        unsigned short* l = &As[buf][h][0][0];
        async_copy16(gA[0] + off, l + lo[0]);
        async_copy16(gA[1] + off, l + lo[1]);
    };
    auto stageB = [&](int t, int buf, int h) {
        const size_t off = (size_t)(t >> 4) * ((size_t)M_DIM * K_LOCAL)
                         + (size_t)((t & 15) << 6) + (size_t)h * (128 * K_LOCAL);
        unsigned short* l = &Bs[buf][h][0][0];
        async_copy16(gB[0] + off, l + lo[0]);
        async_copy16(gB[1] + off, l + lo[1]);
    };

    // Fragment reads: k-chunk c = ks*4 + l4 stored at c ^ (row&7); frag rows
    // are <mult of 16> + l15, so row&7 == l15&7.
    const int swzk0 = ((l4 + 0) ^ (l15 & 7)) * 8;  // ks = 0
    const int swzk1 = ((l4 + 4) ^ (l15 & 7)) * 8;  // ks = 1
    const int hb = wn4 >> 1;                        // B half for this wave
    const int brow_base = (wn4 & 1) * 64 + l15;     // B row within half

    f32x4 acc[8][4] = {};
    bf16x8 aR[8], a1R[8], b0R[4], b1R[4];

    auto LDA = [&](bf16x8* dst, int buf, int mh) {
#pragma unroll
        for (int m = 0; m < 4; ++m) {
            const unsigned short* rp = &As[buf][wm2][mh * 64 + m * 16 + l15][0];
            dst[m * 2 + 0] = *(const bf16x8*)(rp + swzk0);
            dst[m * 2 + 1] = *(const bf16x8*)(rp + swzk1);
        }
    };
    auto LDB = [&](bf16x8* dst, int buf, int nh) {
#pragma unroll
        for (int n = 0; n < 2; ++n) {
            const unsigned short* rp = &Bs[buf][hb][brow_base + nh * 32 + n * 16][0];
            dst[n * 2 + 0] = *(const bf16x8*)(rp + swzk0);
            dst[n * 2 + 1] = *(const bf16x8*)(rp + swzk1);
        }
    };
    auto MFMA16 = [&](const bf16x8* a, const bf16x8* b, int mh, int nh) {
        __builtin_amdgcn_s_setprio(1);
#pragma unroll
        for (int m = 0; m < 4; ++m)
#pragma unroll
            for (int n = 0; n < 2; ++n)
#pragma unroll
                for (int ks = 0; ks < 2; ++ks)
                    acc[mh * 4 + m][nh * 2 + n] = __builtin_amdgcn_mfma_f32_16x16x32_bf16(
                        a[m * 2 + ks], b[n * 2 + ks], acc[mh * 4 + m][nh * 2 + n], 0, 0, 0);
        __builtin_amdgcn_s_setprio(0);
    };

    // Prologue: t0 all 4 units (8 loads), then B0/A0/B1 of t1 (6 loads).
    // VM6 retires exactly t0's 8; {B0,A0,B1}(t1) stay in flight.
    stageA(0, 0, 0); stageA(0, 0, 1); stageB(0, 0, 0); stageB(0, 0, 1);
    stageB(1, 1, 0); stageA(1, 1, 0); stageB(1, 1, 1);
    VM6(); BAR();

    // ONE barrier per phase; stage issued AFTER the MFMA cluster (WAR-provable:
    // last reader's LGKM0 precedes the barrier that precedes the stage-issue).
    for (int i = 0; i < NT / 2; ++i) {
        const int t1 = 2 * i + 1;
        const int t2 = (2 * i + 2) & (NT - 1);
        const int t3 = (2 * i + 3) & (NT - 1);
        // P0: Q00(t)  | stage A1(t1)->buf1.A1 [last read prev P6]
        LDA(aR, 0, 0); LDB(b0R, 0, 0);
        BAR(); LGKM0(); MFMA16(aR, b0R, 0, 0);
        stageA(t1, 1, 1);
        // P1: Q01(t)  | stage B0(t2)->buf0.B0 [last read P0]
        LDB(b1R, 0, 1);
        BAR(); LGKM0(); MFMA16(aR, b1R, 0, 1);
        stageB(t2, 0, 0);
        // P2: Q10(t)  | stage A0(t2)->buf0.A0 [last read P0]
        LDA(a1R, 0, 1);
        BAR(); LGKM0(); MFMA16(a1R, b0R, 1, 0);
        stageA(t2, 0, 0);
        // P3: Q11(t)  | stage B1(t2)->buf0.B1 [last read P1] | VM6 (retire t1)
        BAR(); MFMA16(a1R, b1R, 1, 1);
        stageB(t2, 0, 1);
        VM6();
        // P4: Q00(t1) | stage A1(t2)->buf0.A1 [last read P2]
        LDA(aR, 1, 0); LDB(b0R, 1, 0);
        BAR(); LGKM0(); MFMA16(aR, b0R, 0, 0);
        stageA(t2, 0, 1);
        // P5: Q01(t1) | stage B0(t3)->buf1.B0 [last read P4]
        LDB(b1R, 1, 1);
        BAR(); LGKM0(); MFMA16(aR, b1R, 0, 1);
        stageB(t3, 1, 0);
        // P6: Q10(t1) | stage A0(t3)->buf1.A0 [last read P4]
        LDA(a1R, 1, 1);
        BAR(); LGKM0(); MFMA16(a1R, b0R, 1, 0);
        stageA(t3, 1, 0);
        // P7: Q11(t1) | stage B1(t3)->buf1.B1 [last read P5] | VM6 (retire t2)
        BAR(); MFMA16(a1R, b1R, 1, 1);
        stageB(t3, 1, 1);
        VM6();
    }
    VM0();  // drain outstanding DMA before exit

    // Epilogue: C/D layout col = lane&15, row = (lane>>4)*4 + reg.
#pragma unroll
    for (int m = 0; m < 8; ++m) {
        int row0 = bm0 + wm2 * 128 + m * 16 + l4 * 4;
#pragma unroll
        for (int n = 0; n < 4; ++n) {
            int col = bn0 + wn4 * 64 + n * 16 + l15;
#pragma unroll
            for (int rr = 0; rr < 4; ++rr)
                C[(size_t)(row0 + rr) * N_DIM + col] = acc[m][n][rr];
        }
    }
}

// ---------- Fallback (ws too small): naive fp32 tiled GEMM ----------
__global__ void gemm_naive(const float* __restrict__ A, const float* __restrict__ B,
                           float* __restrict__ C) {
    __shared__ float As[16][17];
    __shared__ float Bs[16][17];
    int tx = threadIdx.x, ty = threadIdx.y;
    int m = blockIdx.y * 16 + ty;
    int n0 = blockIdx.x * 16;
    float accv = 0.f;
    for (int kt = 0; kt < K_DIM; kt += 16) {
        int r = kt >> 10;
        int k = (kt & 1023) + tx;
        As[ty][tx] = A[((size_t)r * M_DIM + m) * K_LOCAL + k];
        Bs[ty][tx] = B[((size_t)r * N_DIM + (n0 + ty)) * K_LOCAL + k];
        __syncthreads();
#pragma unroll
        for (int kk = 0; kk < 16; ++kk) accv += As[ty][kk] * Bs[tx][kk];
        __syncthreads();
    }
    C[(size_t)m * N_DIM + n0 + tx] = accv;
}

extern "C" void kernel_launch(void* const* d_in, const int* in_sizes, int n_in,
                              void* d_out, int out_size, void* d_ws, size_t ws_size,
                              hipStream_t stream) {
    const float* inp = (const float*)d_in[0];
    const float* wgt = (const float*)d_in[1];
    float* out = (float*)d_out;

    const size_t elems = (size_t)M_DIM * K_DIM;              // 33,554,432 per tensor
    const size_t need = 2 * elems * sizeof(unsigned short);  // 128 MiB

    if (ws_size >= need) {
        unsigned short* Abf = (unsigned short*)d_ws;
        unsigned short* Bbf = Abf + elems;
        const int bpt = (int)(elems / 4096);      // 8192 blocks per tensor
        convert_cast<<<bpt * 2, 256, 0, stream>>>(inp, Abf, wgt, Bbf, bpt);
        gemm_bf16<<<256, 512, 0, stream>>>(Abf, Bbf, out);
    } else {
        dim3 grid(N_DIM / 16, M_DIM / 16);
        dim3 block(16, 16);
        gemm_naive<<<grid, block, 0, stream>>>(inp, wgt, out);
    }
}

// Round 9
// 468.276 us; speedup vs baseline: 1.1629x; 1.0894x over previous
//
#include <hip/hip_runtime.h>
#include <cstdint>
#include <cstddef>

// C[4096,4096] = sum_r input[r] @ weight[r]^T  == GEMM M=N=4096, K=8192, fp32 out.
// Phase 1: fp32 -> bf16 cast, R0 version (~80us real; dur_us carries ~170us of
//          fixed non-kernel overhead discovered in R7 — cast is near roofline).
// Phase 2: R13 = R6 (best: 224us, MfmaUtil 55%) minus the explicit LGKM0 full
//          drains. The asm LGKM0 forced all 12 ds_reads to complete before the
//          FIRST MFMA, re-serializing the LDS burst and MFMA burst every phase.
//          Compiler-managed counted lgkmcnt(N) lets the first MFMA start when
//          its own frags land; remaining reads drain UNDER the MFMA cluster.
//          (R8 single-barrier: 268us, reverted. R5 read-ahead: spilled,
//          reverted. R7 fusion: 376us, reverted.)
//          Deep-prefetch slots (R6): P0:A1(t1) P1:B0(t2) P2:A0(t2) P3:B1(t2)
//          P4:A1(t2) P5:B0(t3) P6:A0(t3) P7:B1(t3); vmcnt(6) at P3/P7.

#define M_DIM 4096
#define N_DIM 4096
#define K_DIM 8192
#define K_LOCAL 1024
#define RANKS 8
#define NT 128  // K-tiles: RANKS * (K_LOCAL/64)

typedef __bf16 bf16x8 __attribute__((ext_vector_type(8)));
typedef float f32x4 __attribute__((ext_vector_type(4)));

__device__ __forceinline__ unsigned short f2bf(float f) {
    unsigned int u = __float_as_uint(f);
    unsigned int r = (u + 0x7fffu + ((u >> 16) & 1u)) >> 16;
    return (unsigned short)r;
}

// ---------- Phase 1: linear fp32 -> bf16 cast (R0 version) ----------
__global__ __launch_bounds__(256) void convert_cast(
    const float* __restrict__ srcA, unsigned short* __restrict__ dstA,
    const float* __restrict__ srcB, unsigned short* __restrict__ dstB,
    int blocks_per_tensor) {
    const float* src = srcA;
    unsigned short* dst = dstA;
    int b = blockIdx.x;
    if (b >= blocks_per_tensor) { b -= blocks_per_tensor; src = srcB; dst = dstB; }
    size_t base = (size_t)b * 4096 + threadIdx.x * 4;
#pragma unroll
    for (int i = 0; i < 4; ++i) {
        size_t e = base + i * 1024;
        f32x4 v = __builtin_nontemporal_load((const f32x4*)(src + e));
        ushort4 o;
        o.x = f2bf(v.x); o.y = f2bf(v.y); o.z = f2bf(v.z); o.w = f2bf(v.w);
        *(ushort4*)(dst + e) = o;
    }
}

// ---------- Phase 2: 256^2 deep-prefetch 8-phase bf16 MFMA GEMM ----------
__device__ __forceinline__ void async_copy16(const unsigned short* g, unsigned short* l) {
    __builtin_amdgcn_global_load_lds(
        (const __attribute__((address_space(1))) void*)g,
        (__attribute__((address_space(3))) void*)l,
        16, 0, 0);
}

#define VM6()   asm volatile("s_waitcnt vmcnt(6)" ::: "memory")
#define VM0()   asm volatile("s_waitcnt vmcnt(0)" ::: "memory")
#define BAR()   __builtin_amdgcn_s_barrier()

__global__ __launch_bounds__(512, 2) void gemm_bf16(
    const unsigned short* __restrict__ A,  // [R, M, K_LOCAL] bf16
    const unsigned short* __restrict__ B,  // [R, N, K_LOCAL] bf16
    float* __restrict__ C) {               // [M, N] fp32
    // Per-tensor-half regions: [buf][rowhalf][128 rows][64 k] (128B rows).
    // 16B chunk c of row r stored at chunk c ^ (r & 7) (0 conflicts, R3-R6).
    __shared__ __align__(16) unsigned short As[2][2][128][64];
    __shared__ __align__(16) unsigned short Bs[2][2][128][64];

    const int tid = threadIdx.x;   // 0..511
    const int lane = tid & 63;
    const int wave = tid >> 6;     // 0..7
    const int l15 = lane & 15;
    const int l4 = lane >> 4;      // 0..3
    const int wm2 = wave >> 2;     // 0..1 -> row block *128 (= A half read)
    const int wn4 = wave & 3;      // 0..3 -> col block *64

    // Bijective XCD swizzle: 256 blocks, each XCD owns a 4x8 tile sub-grid.
    const int bid = blockIdx.x;
    const int xcd = bid & 7;
    const int idx = bid >> 3;                       // 0..31
    const int trow = (xcd >> 1) * 4 + (idx >> 3);   // 0..15
    const int tcol = (xcd & 1) * 8 + (idx & 7);     // 0..15
    const int bm0 = trow * 256;
    const int bn0 = tcol * 256;

    // Stage unit = one tensor-half: 128 rows x 64 k x 2B = 16KB = 1024 chunks;
    // li = i*512 + tid: row = li>>3, cpos = li&7, global chunk g = cpos^(row&7).
    const unsigned short* gA[2];
    const unsigned short* gB[2];
    int lo[2];
#pragma unroll
    for (int i = 0; i < 2; ++i) {
        int li = i * 512 + tid;
        int row = li >> 3;
        int g = (li & 7) ^ (row & 7);
        gA[i] = A + (size_t)(bm0 + row) * K_LOCAL + g * 8;
        gB[i] = B + (size_t)(bn0 + row) * K_LOCAL + g * 8;
        lo[i] = li * 8;  // ushort units
    }

    auto stageA = [&](int t, int buf, int h) {
        const size_t off = (size_t)(t >> 4) * ((size_t)M_DIM * K_LOCAL)
                         + (size_t)((t & 15) << 6) + (size_t)h * (128 * K_LOCAL);
        unsigned short* l = &As[buf][h][0][0];
        async_copy16(gA[0] + off, l + lo[0]);
        async_copy16(gA[1] + off, l + lo[1]);
    };
    auto stageB = [&](int t, int buf, int h) {
        const size_t off = (size_t)(t >> 4) * ((size_t)M_DIM * K_LOCAL)
                         + (size_t)((t & 15) << 6) + (size_t)h * (128 * K_LOCAL);
        unsigned short* l = &Bs[buf][h][0][0];
        async_copy16(gB[0] + off, l + lo[0]);
        async_copy16(gB[1] + off, l + lo[1]);
    };

    // Fragment reads: k-chunk c = ks*4 + l4 stored at c ^ (row&7); frag rows
    // are <mult of 16> + l15, so row&7 == l15&7.
    const int swzk0 = ((l4 + 0) ^ (l15 & 7)) * 8;  // ks = 0
    const int swzk1 = ((l4 + 4) ^ (l15 & 7)) * 8;  // ks = 1
    const int hb = wn4 >> 1;                        // B half for this wave
    const int brow_base = (wn4 & 1) * 64 + l15;     // B row within half

    f32x4 acc[8][4] = {};
    bf16x8 aR[8], a1R[8], b0R[4], b1R[4];

    auto LDA = [&](bf16x8* dst, int buf, int mh) {
#pragma unroll
        for (int m = 0; m < 4; ++m) {
            const unsigned short* rp = &As[buf][wm2][mh * 64 + m * 16 + l15][0];
            dst[m * 2 + 0] = *(const bf16x8*)(rp + swzk0);
            dst[m * 2 + 1] = *(const bf16x8*)(rp + swzk1);
        }
    };
    auto LDB = [&](bf16x8* dst, int buf, int nh) {
#pragma unroll
        for (int n = 0; n < 2; ++n) {
            const unsigned short* rp = &Bs[buf][hb][brow_base + nh * 32 + n * 16][0];
            dst[n * 2 + 0] = *(const bf16x8*)(rp + swzk0);
            dst[n * 2 + 1] = *(const bf16x8*)(rp + swzk1);
        }
    };
    auto MFMA16 = [&](const bf16x8* a, const bf16x8* b, int mh, int nh) {
        __builtin_amdgcn_s_setprio(1);
#pragma unroll
        for (int m = 0; m < 4; ++m)
#pragma unroll
            for (int n = 0; n < 2; ++n)
#pragma unroll
                for (int ks = 0; ks < 2; ++ks)
                    acc[mh * 4 + m][nh * 2 + n] = __builtin_amdgcn_mfma_f32_16x16x32_bf16(
                        a[m * 2 + ks], b[n * 2 + ks], acc[mh * 4 + m][nh * 2 + n], 0, 0, 0);
        __builtin_amdgcn_s_setprio(0);
    };

    // Prologue: t0 all 4 units (8 loads), then B0/A0/B1 of t1 (6 loads).
    // VM6 retires exactly t0's 8; {B0,A0,B1}(t1) stay in flight.
    stageA(0, 0, 0); stageA(0, 0, 1); stageB(0, 0, 0); stageB(0, 0, 1);
    stageB(1, 1, 0); stageA(1, 1, 0); stageB(1, 1, 1);
    VM6(); BAR();

    // Per phase: {reads; stage; BAR; MFMA16; BAR}. No explicit lgkm drain —
    // the compiler emits counted lgkmcnt(N) per MFMA operand, so later reads
    // drain under earlier MFMAs (within-phase overlap, no extra registers).
    for (int i = 0; i < NT / 2; ++i) {
        const int t1 = 2 * i + 1;
        const int t2 = (2 * i + 2) & (NT - 1);
        const int t3 = (2 * i + 3) & (NT - 1);
        // P0: Q00(t) | stage A1(t1)  [buf1.A1 read last at prev P6]
        LDA(aR, 0, 0); LDB(b0R, 0, 0); stageA(t1, 1, 1);
        BAR(); MFMA16(aR, b0R, 0, 0); BAR();
        // P1: Q01(t) | stage B0(t2)  [buf0.B0 read at P0]
        LDB(b1R, 0, 1); stageB(t2, 0, 0);
        BAR(); MFMA16(aR, b1R, 0, 1); BAR();
        // P2: Q10(t) | stage A0(t2)  [buf0.A0 read at P0]
        LDA(a1R, 0, 1); stageA(t2, 0, 0);
        BAR(); MFMA16(a1R, b0R, 1, 0); BAR();
        // P3: Q11(t) | stage B1(t2)  [buf0.B1 read at P1] | vmcnt(6)
        stageB(t2, 0, 1);
        BAR(); MFMA16(a1R, b1R, 1, 1); VM6(); BAR();
        // P4: Q00(t1) | stage A1(t2) [buf0.A1 read at P2]
        LDA(aR, 1, 0); LDB(b0R, 1, 0); stageA(t2, 0, 1);
        BAR(); MFMA16(aR, b0R, 0, 0); BAR();
        // P5: Q01(t1) | stage B0(t3) [buf1.B0 read at P4]
        LDB(b1R, 1, 1); stageB(t3, 1, 0);
        BAR(); MFMA16(aR, b1R, 0, 1); BAR();
        // P6: Q10(t1) | stage A0(t3) [buf1.A0 read at P4]
        LDA(a1R, 1, 1); stageA(t3, 1, 0);
        BAR(); MFMA16(a1R, b0R, 1, 0); BAR();
        // P7: Q11(t1) | stage B1(t3) [buf1.B1 read at P5] | vmcnt(6)
        stageB(t3, 1, 1);
        BAR(); MFMA16(a1R, b1R, 1, 1); VM6(); BAR();
    }
    VM0();  // drain outstanding DMA before exit

    // Epilogue: C/D layout col = lane&15, row = (lane>>4)*4 + reg.
#pragma unroll
    for (int m = 0; m < 8; ++m) {
        int row0 = bm0 + wm2 * 128 + m * 16 + l4 * 4;
#pragma unroll
        for (int n = 0; n < 4; ++n) {
            int col = bn0 + wn4 * 64 + n * 16 + l15;
#pragma unroll
            for (int rr = 0; rr < 4; ++rr)
                C[(size_t)(row0 + rr) * N_DIM + col] = acc[m][n][rr];
        }
    }
}

// ---------- Fallback (ws too small): naive fp32 tiled GEMM ----------
__global__ void gemm_naive(const float* __restrict__ A, const float* __restrict__ B,
                           float* __restrict__ C) {
    __shared__ float As[16][17];
    __shared__ float Bs[16][17];
    int tx = threadIdx.x, ty = threadIdx.y;
    int m = blockIdx.y * 16 + ty;
    int n0 = blockIdx.x * 16;
    float accv = 0.f;
    for (int kt = 0; kt < K_DIM; kt += 16) {
        int r = kt >> 10;
        int k = (kt & 1023) + tx;
        As[ty][tx] = A[((size_t)r * M_DIM + m) * K_LOCAL + k];
        Bs[ty][tx] = B[((size_t)r * N_DIM + (n0 + ty)) * K_LOCAL + k];
        __syncthreads();
#pragma unroll
        for (int kk = 0; kk < 16; ++kk) accv += As[ty][kk] * Bs[tx][kk];
        __syncthreads();
    }
    C[(size_t)m * N_DIM + n0 + tx] = accv;
}

extern "C" void kernel_launch(void* const* d_in, const int* in_sizes, int n_in,
                              void* d_out, int out_size, void* d_ws, size_t ws_size,
                              hipStream_t stream) {
    const float* inp = (const float*)d_in[0];
    const float* wgt = (const float*)d_in[1];
    float* out = (float*)d_out;

    const size_t elems = (size_t)M_DIM * K_DIM;              // 33,554,432 per tensor
    const size_t need = 2 * elems * sizeof(unsigned short);  // 128 MiB

    if (ws_size >= need) {
        unsigned short* Abf = (unsigned short*)d_ws;
        unsigned short* Bbf = Abf + elems;
        const int bpt = (int)(elems / 4096);      // 8192 blocks per tensor
        convert_cast<<<bpt * 2, 256, 0, stream>>>(inp, Abf, wgt, Bbf, bpt);
        gemm_bf16<<<256, 512, 0, stream>>>(Abf, Bbf, out);
    } else {
        dim3 grid(N_DIM / 16, M_DIM / 16);
        dim3 block(16, 16);
        gemm_naive<<<grid, block, 0, stream>>>(inp, wgt, out);
    }
}